// Round 3
// baseline (602.512 us; speedup 1.0000x reference)
//
#include <hip/hip_runtime.h>

typedef __attribute__((ext_vector_type(4))) float floatx4;

// ---------------------------------------------------------------------------
// pack 4 floats (already fp8-representable / clipped) into 4 e4m3 bytes, RNE
// ---------------------------------------------------------------------------
__device__ __forceinline__ unsigned int pack4_fp8(float f0, float f1, float f2, float f3) {
    int v = __builtin_amdgcn_cvt_pk_fp8_f32(f0, f1, 0, false);   // bytes 0,1
    v = __builtin_amdgcn_cvt_pk_fp8_f32(f2, f3, v, true);        // bytes 2,3
    return (unsigned int)v;
}

// ---------------------------------------------------------------------------
// Kernel 0: classify the weight buffer's on-device dtype.
// fp8-exact values: as f32, low 20 mantissa bits are 0; as bf16, low nibble 0.
// flag: 0 = raw fp8 bytes, 1 = bf16-upcast, 2 = f32-upcast.
// ---------------------------------------------------------------------------
__global__ void detect_kernel(const unsigned int* __restrict__ W, int* __restrict__ flag) {
    __shared__ int ok[2];  // [f32ok, bf16ok]
    if (threadIdx.x == 0) { ok[0] = 1; ok[1] = 1; }
    __syncthreads();
    int f32ok = 1, bf16ok = 1;
#pragma unroll
    for (int i = 0; i < 16; ++i) {
        unsigned int w = W[threadIdx.x * 16 + i];   // first 16 KB of buffer
        if (w & 0x000FFFFFu) f32ok = 0;
        if (w & 0x000F000Fu) bf16ok = 0;
    }
    if (!f32ok)  atomicAnd(&ok[0], 0);
    if (!bf16ok) atomicAnd(&ok[1], 0);
    __syncthreads();
    if (threadIdx.x == 0) *flag = ok[0] ? 2 : (ok[1] ? 1 : 0);
}

// ---------------------------------------------------------------------------
// Kernel 1: quantize x (fp32) -> q (fp8 e4m3fn), q = clip(x/s, +-448)
// ---------------------------------------------------------------------------
__global__ void quant_kernel(const float* __restrict__ x,
                             unsigned int* __restrict__ q,
                             const float* __restrict__ iscale, int n8) {
    int i = blockIdx.x * blockDim.x + threadIdx.x;
    if (i >= n8) return;
    float s = iscale[0];
    const float4* xv = (const float4*)x;
    float4 a = xv[2 * i];
    float4 b = xv[2 * i + 1];
    float v[8] = {a.x, a.y, a.z, a.w, b.x, b.y, b.z, b.w};
#pragma unroll
    for (int j = 0; j < 8; ++j) {
        float t = v[j] / s;
        v[j] = fminf(fmaxf(t, -448.0f), 448.0f);
    }
    q[2 * i]     = pack4_fp8(v[0], v[1], v[2], v[3]);
    q[2 * i + 1] = pack4_fp8(v[4], v[5], v[6], v[7]);
}

// ---------------------------------------------------------------------------
// Kernel 2 (x3 modes): ingest weight [K,N] (any of the 3 dtypes) -> Wt [N,K]
// fp8 bytes, via 64x64 LDS tile. Whole kernel no-ops unless *flag == MODE
// (flag is global & uniform -> no barrier divergence).
// ---------------------------------------------------------------------------
template <int MODE>
__global__ void ingest_kernel(const unsigned char* __restrict__ W,
                              unsigned char* __restrict__ Wt,
                              const int* __restrict__ flag, int K, int N) {
    if (*flag != MODE) return;
    __shared__ __align__(16) unsigned char tile[64][68];  // [k][n], +4 pad
    const int k0 = blockIdx.y * 64;
    const int n0 = blockIdx.x * 64;
    const int t = threadIdx.x;          // 256 threads
    const int kr = t >> 2;              // k-row within tile
    const int cg = (t & 3) * 16;        // n-column group (16 values)
    const size_t eidx = (size_t)(k0 + kr) * N + (n0 + cg);  // element index

    unsigned int w4[4];
    if constexpr (MODE == 0) {          // raw fp8 bytes
        uint4 v = *(const uint4*)(W + eidx);
        w4[0] = v.x; w4[1] = v.y; w4[2] = v.z; w4[3] = v.w;
    } else if constexpr (MODE == 1) {   // bf16-upcast (2 B/elem)
        const uint4* p = (const uint4*)((const unsigned short*)W + eidx);
        uint4 A0 = p[0], A1 = p[1];
        unsigned int uw[8] = {A0.x, A0.y, A0.z, A0.w, A1.x, A1.y, A1.z, A1.w};
#pragma unroll
        for (int g = 0; g < 4; ++g) {
            float f0 = __uint_as_float((uw[2 * g] & 0xFFFFu) << 16);
            float f1 = __uint_as_float((uw[2 * g] >> 16) << 16);
            float f2 = __uint_as_float((uw[2 * g + 1] & 0xFFFFu) << 16);
            float f3 = __uint_as_float((uw[2 * g + 1] >> 16) << 16);
            w4[g] = pack4_fp8(f0, f1, f2, f3);
        }
    } else {                            // f32-upcast (4 B/elem)
        const float4* p = (const float4*)((const float*)W + eidx);
#pragma unroll
        for (int g = 0; g < 4; ++g) {
            float4 f = p[g];
            w4[g] = pack4_fp8(f.x, f.y, f.z, f.w);
        }
    }
#pragma unroll
    for (int g = 0; g < 4; ++g)
        *(unsigned int*)&tile[kr][cg + 4 * g] = w4[g];   // 4B-aligned (68%4==0)
    __syncthreads();

    const int nr = t >> 2;
    const int kg = (t & 3) * 16;
    uint4 o;
    unsigned int w[4];
#pragma unroll
    for (int g = 0; g < 4; ++g) {
        unsigned int b0 = tile[kg + g * 4 + 0][nr];
        unsigned int b1 = tile[kg + g * 4 + 1][nr];
        unsigned int b2 = tile[kg + g * 4 + 2][nr];
        unsigned int b3 = tile[kg + g * 4 + 3][nr];
        w[g] = b0 | (b1 << 8) | (b2 << 16) | (b3 << 24);
    }
    o.x = w[0]; o.y = w[1]; o.z = w[2]; o.w = w[3];
    *(uint4*)(Wt + (size_t)(n0 + nr) * K + k0 + kg) = o;  // 16B-aligned
}

// ---------------------------------------------------------------------------
// Kernel 3: fp8 GEMM. 128x128 tile, BK=64, explicit VGPR staging.
// ROUND-3 FIX: LDS row stride 80 (was 72) -> ds_write_b128 addresses are
// 16B-aligned (72 made odd rows 8-mod-16 => misaligned b128 => writes dropped
// => LDS stayed zero => acc==0 => bias-only output, the observed failure).
// Bank math @80: lane bank = (20*(l&15) + 2*(l>>4)) % 32 -> exact 2-way = free.
// ---------------------------------------------------------------------------
__global__ __launch_bounds__(256) void gemm_fp8_kernel(
    const unsigned char* __restrict__ A,   // [M,K] fp8
    const unsigned char* __restrict__ Bt,  // [N,K] fp8
    float* __restrict__ C,                 // [M,N] fp32
    const float* __restrict__ bias,        // [N]
    const float* __restrict__ wscale,
    const float* __restrict__ iscale,
    int M, int N, int K) {
    constexpr int ROWB = 80;  // 64 data + 16 pad; multiple of 16!
    __shared__ __align__(16) unsigned char As[128 * ROWB];  // 10 KB
    __shared__ __align__(16) unsigned char Bs[128 * ROWB];  // 10 KB

    const int tid  = threadIdx.x;
    const int lane = tid & 63;
    const int wave = tid >> 6;
    const int wm = wave >> 1;
    const int wn = wave & 1;
    const int bm = blockIdx.y * 128;
    const int bn = blockIdx.x * 128;

    floatx4 acc[4][4] = {};

    const int c0 = tid, c1 = tid + 256;
    const int r0 = c0 >> 2, o0 = (c0 & 3) * 16;
    const int r1 = c1 >> 2, o1 = (c1 & 3) * 16;
    const unsigned char* pa0 = A  + (size_t)(bm + r0) * K + o0;
    const unsigned char* pa1 = A  + (size_t)(bm + r1) * K + o1;
    const unsigned char* pb0 = Bt + (size_t)(bn + r0) * K + o0;
    const unsigned char* pb1 = Bt + (size_t)(bn + r1) * K + o1;
    uint4* const sa0 = (uint4*)&As[r0 * ROWB + o0];  // 80*r+o : 16B-aligned
    uint4* const sa1 = (uint4*)&As[r1 * ROWB + o1];
    uint4* const sb0 = (uint4*)&Bs[r0 * ROWB + o0];
    uint4* const sb1 = (uint4*)&Bs[r1 * ROWB + o1];

    const int arow = wm * 64 + (lane & 15);
    const int brow = wn * 64 + (lane & 15);
    const int aq8  = (lane >> 4) * 8;

    for (int k0 = 0; k0 < K; k0 += 64) {
        uint4 va0 = *(const uint4*)pa0; pa0 += 64;
        uint4 va1 = *(const uint4*)pa1; pa1 += 64;
        uint4 vb0 = *(const uint4*)pb0; pb0 += 64;
        uint4 vb1 = *(const uint4*)pb1; pb1 += 64;
        __syncthreads();
        *sa0 = va0; *sa1 = va1;
        *sb0 = vb0; *sb1 = vb1;
        __syncthreads();

        long af[2][4], bf[2][4];
#pragma unroll
        for (int im = 0; im < 4; ++im) {
            af[0][im] = *(const long*)&As[(arow + im * 16) * ROWB + aq8];
            af[1][im] = *(const long*)&As[(arow + im * 16) * ROWB + aq8 + 32];
            bf[0][im] = *(const long*)&Bs[(brow + im * 16) * ROWB + aq8];
            bf[1][im] = *(const long*)&Bs[(brow + im * 16) * ROWB + aq8 + 32];
        }

#pragma unroll
        for (int ks = 0; ks < 2; ++ks)
#pragma unroll
            for (int im = 0; im < 4; ++im)
#pragma unroll
                for (int in = 0; in < 4; ++in)
                    acc[im][in] = __builtin_amdgcn_mfma_f32_16x16x32_fp8_fp8(
                        af[ks][im], bf[ks][in], acc[im][in], 0, 0, 0);
    }

    const float scale = iscale[0] * wscale[0];
    const int row0 = bm + wm * 64 + ((lane >> 4) << 2);
    const int col0 = bn + wn * 64 + (lane & 15);
#pragma unroll
    for (int in = 0; in < 4; ++in) {
        const int col = col0 + in * 16;
        const float bv = bias[col];
#pragma unroll
        for (int im = 0; im < 4; ++im) {
            const int row = row0 + im * 16;
            float* cp = C + (size_t)row * N + col;
#pragma unroll
            for (int r = 0; r < 4; ++r)
                cp[(size_t)r * N] = acc[im][in][r] * scale + bv;
        }
    }
}

extern "C" void kernel_launch(void* const* d_in, const int* in_sizes, int n_in,
                              void* d_out, int out_size, void* d_ws, size_t ws_size,
                              hipStream_t stream) {
    const float* x          = (const float*)d_in[0];
    const unsigned char* w  = (const unsigned char*)d_in[1];
    const float* wscale     = (const float*)d_in[2];
    const float* iscale     = (const float*)d_in[3];
    const float* bias       = (const float*)d_in[4];
    float* out              = (float*)d_out;

    const int D_OUT = in_sizes[4];            // 8192
    const int D_IN  = in_sizes[1] / D_OUT;    // 2048
    const int M     = in_sizes[0] / D_IN;     // 8192

    int* flag         = (int*)d_ws;
    unsigned char* q  = (unsigned char*)d_ws + 256;
    unsigned char* wt = q + (size_t)M * D_IN;

    detect_kernel<<<1, 256, 0, stream>>>((const unsigned int*)w, flag);
    const int n8 = (M * D_IN) / 8;
    quant_kernel<<<(n8 + 255) / 256, 256, 0, stream>>>(x, (unsigned int*)q, iscale, n8);
    dim3 tg(D_OUT / 64, D_IN / 64);
    ingest_kernel<0><<<tg, 256, 0, stream>>>(w, wt, flag, D_IN, D_OUT);
    ingest_kernel<1><<<tg, 256, 0, stream>>>(w, wt, flag, D_IN, D_OUT);
    ingest_kernel<2><<<tg, 256, 0, stream>>>(w, wt, flag, D_IN, D_OUT);
    gemm_fp8_kernel<<<dim3(D_OUT / 128, M / 128), 256, 0, stream>>>(
        q, wt, out, bias, wscale, iscale, M, D_OUT, D_IN);
}